// Round 1
// baseline (37851.715 us; speedup 1.0000x reference)
//
#include <hip/hip_runtime.h>

#define NHIDC 1024
#define BSZ   128
#define TLEN  256
#define SLOT  (BSZ*NHIDC)   // 131072 floats per state slot

using bf16x8 = __attribute__((ext_vector_type(8))) short;
using f32x4  = __attribute__((ext_vector_type(4))) float;

__device__ inline short f2bf(float f){
  union {float f; unsigned u;} v; v.f = f;
  unsigned u = v.u;
  unsigned r = u + 0x7fffu + ((u >> 16) & 1u);
  return (short)(r >> 16);
}

__device__ inline float bact(int act, float x){
  switch(act){
    case 0: return tanhf(x);
    case 1: return 1.f/(1.f+__expf(-x));
    case 2: return x > 0.f ? x : 0.f;
    default: return x;
  }
}

// Transpose-convert: D[n][k] (bf16) = S[k][n] (f32), S is K x 2048, per blockIdx.z matrix.
__global__ __launch_bounds__(256) void transpose_bf16(const float* __restrict__ src,
                                                      short* __restrict__ dst, int K){
  const size_t mat = blockIdx.z;
  const float* S = src + mat * (size_t)K * 2048;
  short* D = dst + mat * (size_t)K * 2048;
  __shared__ float tile[32][33];
  int n0 = blockIdx.x * 32;
  int k0 = blockIdx.y * 32;
  int tx = threadIdx.x & 31, ty = threadIdx.x >> 5;
  #pragma unroll
  for (int i=0;i<4;i++){
    tile[ty + i*8][tx] = S[(size_t)(k0 + ty + i*8)*2048 + n0 + tx];
  }
  __syncthreads();
  #pragma unroll
  for (int i=0;i<4;i++){
    int n = n0 + ty + i*8;
    D[(size_t)n*K + k0 + tx] = f2bf(tile[tx][ty + i*8]);
  }
}

// Gated matmul stage. Computes, for gene g (selected by blockIdx.y):
//   ch = A @ W   (A: 128 x K fp32 -> bf16 on the fly; W: bf16 [2048][K] row-major, transposed)
//   sout = sprev + sigmoid(ch[:, :1024]) * (act(ch[:, 1024:]) - sprev)
// g = (weight_index, sprev_slot, sout_slot, act)
// STAGE0: A = [x_t | h]  (K=2048), h = states slot 9.
template<bool STAGE0>
__global__ __launch_bounds__(256) void stage_kernel(
    float* __restrict__ states, const short* __restrict__ Wbase, int K,
    const float* __restrict__ x, int t,
    int4 ga, int4 gb, int4 gc)
{
  int4 g = (blockIdx.y==0) ? ga : (blockIdx.y==1 ? gb : gc);
  const short* W = Wbase + (size_t)g.x * (size_t)2048 * (size_t)K;
  const float* sprev = states + (size_t)g.y * SLOT;
  float* sout = states + (size_t)g.z * SLOT;
  const int act = g.w;
  const float* h9 = states + (size_t)9 * SLOT;

  const int lane = threadIdx.x & 63;
  const int wave = threadIdx.x >> 6;
  const int m = lane & 15;
  const int q = lane >> 4;

  const int col0 = blockIdx.x * 16;       // paired-column tile base (j and j+1024)
  const int nC = col0 + m;
  const int nH = nC + 1024;
  const short* wC = W + (size_t)nC * K;
  const short* wH = W + (size_t)nH * K;

  const int rowbase = wave * 32;          // 2 row-tiles (16 rows each) per wave

  f32x4 accC0 = {0.f,0.f,0.f,0.f}, accC1 = {0.f,0.f,0.f,0.f};
  f32x4 accH0 = {0.f,0.f,0.f,0.f}, accH1 = {0.f,0.f,0.f,0.f};

  for (int k0 = 0; k0 < K; k0 += 32) {
    const int k = k0 + q*8;
    bf16x8 bC = *(const bf16x8*)(wC + k);
    bf16x8 bH = *(const bf16x8*)(wH + k);

    const float* p0;
    const float* p1;
    if (STAGE0) {
      const int b0 = rowbase + m;
      if (k0 < 1024) {
        p0 = x + ((size_t)b0*TLEN + t)*NHIDC + k;
        p1 = x + ((size_t)(b0+16)*TLEN + t)*NHIDC + k;
      } else {
        p0 = h9 + (size_t)b0*NHIDC + (k - 1024);
        p1 = h9 + (size_t)(b0+16)*NHIDC + (k - 1024);
      }
    } else {
      p0 = sprev + (size_t)(rowbase + m)*NHIDC + k;
      p1 = p0 + (size_t)16*NHIDC;
    }
    float4 u0a = *(const float4*)(p0);
    float4 u0b = *(const float4*)(p0 + 4);
    float4 u1a = *(const float4*)(p1);
    float4 u1b = *(const float4*)(p1 + 4);

    bf16x8 a0, a1;
    a0[0]=f2bf(u0a.x); a0[1]=f2bf(u0a.y); a0[2]=f2bf(u0a.z); a0[3]=f2bf(u0a.w);
    a0[4]=f2bf(u0b.x); a0[5]=f2bf(u0b.y); a0[6]=f2bf(u0b.z); a0[7]=f2bf(u0b.w);
    a1[0]=f2bf(u1a.x); a1[1]=f2bf(u1a.y); a1[2]=f2bf(u1a.z); a1[3]=f2bf(u1a.w);
    a1[4]=f2bf(u1b.x); a1[5]=f2bf(u1b.y); a1[6]=f2bf(u1b.z); a1[7]=f2bf(u1b.w);

    accC0 = __builtin_amdgcn_mfma_f32_16x16x32_bf16(a0, bC, accC0, 0, 0, 0);
    accC1 = __builtin_amdgcn_mfma_f32_16x16x32_bf16(a1, bC, accC1, 0, 0, 0);
    accH0 = __builtin_amdgcn_mfma_f32_16x16x32_bf16(a0, bH, accH0, 0, 0, 0);
    accH1 = __builtin_amdgcn_mfma_f32_16x16x32_bf16(a1, bH, accH1, 0, 0, 0);
  }

  // Epilogue: C/D layout col=lane&15, row=(lane>>4)*4+reg
  #pragma unroll
  for (int rt=0; rt<2; rt++){
    f32x4 aC = rt ? accC1 : accC0;
    f32x4 aH = rt ? accH1 : accH0;
    #pragma unroll
    for (int i=0;i<4;i++){
      int b = rowbase + rt*16 + q*4 + i;
      int j = col0 + m;
      float sp = sprev[(size_t)b*NHIDC + j];
      float c  = 1.f/(1.f+__expf(-aC[i]));
      float hv = bact(act, aH[i]);
      sout[(size_t)b*NHIDC + j] = sp + c*(hv - sp);
    }
  }
}

// mean of slots 1..8 -> h (slot 9), output slab, and tail copy at t==T-1
__global__ __launch_bounds__(256) void mean_kernel(float* __restrict__ states,
                                                   float* __restrict__ out, int t){
  int idx = blockIdx.x*blockDim.x + threadIdx.x;  // 0..131071
  float s = 0.f;
  #pragma unroll
  for (int i=1;i<=8;i++) s += states[(size_t)i*SLOT + idx];
  s *= 0.125f;
  states[(size_t)9*SLOT + idx] = s;
  int b = idx >> 10, j = idx & 1023;
  out[((size_t)b*TLEN + t)*NHIDC + j] = s;
  if (t == TLEN-1) out[(size_t)BSZ*TLEN*NHIDC + idx] = s;
}

extern "C" void kernel_launch(void* const* d_in, const int* in_sizes, int n_in,
                              void* d_out, int out_size, void* d_ws, size_t ws_size,
                              hipStream_t stream) {
  const float* x  = (const float*)d_in[0];   // (128, 256, 1024)
  const float* h0 = (const float*)d_in[1];   // (1, 128, 1024)
  const float* W0 = (const float*)d_in[2];   // (2048, 2048)
  const float* Ws = (const float*)d_in[3];   // (8, 1024, 2048)
  float* out = (float*)d_out;

  // ws layout: [0) W0T bf16 8MB | [8MB) WsT bf16 32MB | [40MB) states 10 slots fp32 (5MB)
  char* wsb = (char*)d_ws;
  short* W0T = (short*)wsb;
  short* WsT = (short*)(wsb + (size_t)8*1024*1024);
  float* states = (float*)(wsb + (size_t)40*1024*1024);

  transpose_bf16<<<dim3(64,64,1),256,0,stream>>>(W0, W0T, 2048);
  transpose_bf16<<<dim3(64,32,8),256,0,stream>>>(Ws, WsT, 1024);

  hipMemcpyAsync(states + (size_t)9*SLOT, h0, (size_t)SLOT*sizeof(float),
                 hipMemcpyDeviceToDevice, stream);

  const int4 gz = make_int4(0,0,0,0);
  for (int t=0; t<TLEN; t++){
    // stage0: ch=[x|h]@W0 ; s0 = h + sig(cC)*(tanh(cH)-h)   (slot9 -> slot0)
    stage_kernel<true><<<dim3(64,1),256,0,stream>>>(states, W0T, 2048, x, t,
        make_int4(0,9,0,0), gz, gz);
    // g0: sigmoid, sprev s0 -> s1
    stage_kernel<false><<<dim3(64,1),256,0,stream>>>(states, WsT, 1024, nullptr, 0,
        make_int4(0,0,1,1), gz, gz);
    // g1: relu s1->s2 ; g2: relu s1->s3 ; g3: identity s1->s4
    stage_kernel<false><<<dim3(64,3),256,0,stream>>>(states, WsT, 1024, nullptr, 0,
        make_int4(1,1,2,2), make_int4(2,1,3,2), make_int4(3,1,4,3));
    // g4: tanh s2->s5 ; g6: tanh s3->s7
    stage_kernel<false><<<dim3(64,2),256,0,stream>>>(states, WsT, 1024, nullptr, 0,
        make_int4(4,2,5,0), make_int4(6,3,7,0), gz);
    // g5: sigmoid s5->s6 ; g7: relu s5->s8
    stage_kernel<false><<<dim3(64,2),256,0,stream>>>(states, WsT, 1024, nullptr, 0,
        make_int4(5,5,6,1), make_int4(7,5,8,2), gz);
    // mean(s1..s8) -> h, out[:,t,:], tail at t==255
    mean_kernel<<<dim3(512,1,1),256,0,stream>>>(states, out, t);
  }
}